// Round 8
// baseline (3860.403 us; speedup 1.0000x reference)
//
#include <hip/hip_runtime.h>

#define Bn 128
#define Wn 64

typedef _Float16 h2 __attribute__((ext_vector_type(2)));

// ---- precomputed device state (written by prologue kernels each launch) ----
__device__ unsigned g_ep16[Bn * Wn * 128];   // eproj f16 pairs [b][w][128]
__device__ float4 g_encfc[Bn * Wn];          // fc_w[:, :256] @ enc  per (b,w)
__device__ float4 g_encfcf[Bn * Wn];         // fcf_w[:, 256:] @ enc per (b,w)
// coalesced f16 weight streams, element [i] at +1024*i, lane-consecutive tid
__device__ uint4 g_w1s[16 * 1024];           // w1[h|c]: thread(e=tid>>2,kq=tid&3)  (256 KB)
__device__ uint4 g_whs[32 * 1024];           // w_hh: thread=row                    (512 KB)

__device__ __forceinline__ float ftanh(float x) {
  float p = __builtin_exp2f(x * 2.885390081777927f);
  return 1.0f - 2.0f * __builtin_amdgcn_rcpf(p + 1.0f);
}
__device__ __forceinline__ float fsigm(float x) {
  float p = __builtin_exp2f(-x * 1.4426950408889634f);
  return __builtin_amdgcn_rcpf(1.0f + p);
}
__device__ __forceinline__ float dot4(float4 a, float4 b) {
  return a.x * b.x + a.y * b.y + a.z * b.z + a.w * b.w;
}
__device__ __forceinline__ float fd2(unsigned w, unsigned h, float acc) {
  h2 a = __builtin_bit_cast(h2, w), b = __builtin_bit_cast(h2, h);
#if __has_builtin(__builtin_amdgcn_fdot2)
  return __builtin_amdgcn_fdot2(a, b, acc, false);
#else
  return acc + (float)a.x * (float)b.x + (float)a.y * (float)b.y;
#endif
}
__device__ __forceinline__ float fd2x4u(uint4 w, uint4 h, float acc) {
  acc = fd2(w.x, h.x, acc);
  acc = fd2(w.y, h.y, acc);
  acc = fd2(w.z, h.z, acc);
  acc = fd2(w.w, h.w, acc);
  return acc;
}
__device__ __forceinline__ unsigned pk(float a, float b) {
  h2 h = {(_Float16)a, (_Float16)b};
  return __builtin_bit_cast(unsigned, h);
}

// ---------------- pack weights into [i][tid] coalesced f16 streams ----------------
__global__ __launch_bounds__(256) void pack_kernel(const float* __restrict__ w1,
                                                   const float* __restrict__ w_hh) {
  int idx = blockIdx.x * 256 + threadIdx.x;  // 49152 tasks
  const float* src;
  uint4* dst;
  if (idx < 16 * 1024) {
    int i = idx >> 10, t = idx & 1023;
    int e = t >> 2, kq = t & 3;
    src = w1 + (size_t)e * 768 + 128 * kq + 8 * i;  // cols 0..511 = [W1h|W1c]
    dst = g_w1s + idx;
  } else {
    int j = idx - 16 * 1024;
    if (j >= 32 * 1024) return;
    int i = j >> 10, row = j & 1023;
    src = w_hh + (size_t)row * 256 + 8 * i;
    dst = g_whs + j;
  }
  uint4 o;
  o.x = pk(src[0], src[1]); o.y = pk(src[2], src[3]);
  o.z = pk(src[4], src[5]); o.w = pk(src[6], src[7]);
  *dst = o;
}

// ---------------- eproj: b1 + W1e @ enc -> f16 pairs ----------------
__global__ __launch_bounds__(256) void eproj_kernel(const float* __restrict__ enc,
                                                    const float* __restrict__ w1,
                                                    const float* __restrict__ b1) {
  __shared__ __align__(16) float4 encs[16][64];
  __shared__ float accs[16][256];
  const int m0 = blockIdx.x * 16;
  const int tid = threadIdx.x;
  const float4* eg = (const float4*)(enc + (size_t)m0 * 256);
#pragma unroll
  for (int i = 0; i < 4; i++) {
    int idx = tid + 256 * i;
    encs[idx >> 6][idx & 63] = eg[idx];
  }
  __syncthreads();
  const int e = tid;
  float acc[16];
#pragma unroll
  for (int i = 0; i < 16; i++) acc[i] = 0.f;
  const float4* wrow = (const float4*)(w1 + e * 768 + 512);
  for (int k4 = 0; k4 < 64; k4++) {
    float4 wv = wrow[k4];
#pragma unroll
    for (int i = 0; i < 16; i++) acc[i] += dot4(wv, encs[i][k4]);
  }
  float bb = b1[e];
#pragma unroll
  for (int i = 0; i < 16; i++) accs[i][e] = acc[i] + bb;
  __syncthreads();
#pragma unroll
  for (int r = 0; r < 8; r++) {
    int idx = r * 256 + tid;
    int i = idx >> 7, jp = idx & 127;
    g_ep16[(size_t)(m0 + i) * 128 + jp] = pk(accs[i][2 * jp], accs[i][2 * jp + 1]);
  }
}

// ---------------- ENCFC / ENCFCF precompute ----------------
__global__ __launch_bounds__(256) void encfc_kernel(const float* __restrict__ enc,
                                                    const float* __restrict__ fc_w,
                                                    const float* __restrict__ fcf_w) {
  __shared__ __align__(16) float4 encs[16][64];
  const int m0 = blockIdx.x * 16;
  const int tid = threadIdx.x;
  const float4* eg = (const float4*)(enc + (size_t)m0 * 256);
#pragma unroll
  for (int i = 0; i < 4; i++) {
    int idx = tid + 256 * i;
    encs[idx >> 6][idx & 63] = eg[idx];
  }
  __syncthreads();
  if (tid < 128) {
    const int r = tid >> 3, o = tid & 7;
    const float* wr = (o < 4) ? (fc_w + o * 260) : (fcf_w + (o - 4) * 512 + 256);
    const float4* w4 = (const float4*)wr;
    float a = 0.f;
#pragma unroll 8
    for (int k = 0; k < 64; k++) a += dot4(w4[k], encs[r][k]);
    if (o < 4) ((float*)&g_encfc[m0 + r])[o] = a;
    else ((float*)&g_encfcf[m0 + r])[o - 4] = a;
  }
}

// ---------------- decoder: ONE 1024-thread WG per chain, zero cross-WG sync ----------------
__global__ __launch_bounds__(1024, 1) void decoder_kernel(
    const float* __restrict__ yhist, const float* __restrict__ w2,
    const float* __restrict__ w_ih, const float* __restrict__ b_ih,
    const float* __restrict__ b_hh,
    const float* __restrict__ fc_w, const float* __restrict__ fc_b,
    const float* __restrict__ fcf_w, const float* __restrict__ fcf_b,
    float* __restrict__ out) {
  __shared__ __align__(16) unsigned st_l[256];  // h pairs [0..128) | c pairs [128..256)
  __shared__ float hcp_l[256];
  __shared__ float att_l[64];
  __shared__ float ag_l[1024];                  // gate rows (i:0..255,f,g,o)
  __shared__ float w2_l[256];
  __shared__ unsigned ep_l[64 * 132];           // eproj pairs [w][p], stride 132
  __shared__ __align__(16) float4 yh_l[64];
  __shared__ float fcy_l[16];
  __shared__ float fcb_l[4];

  const int b = blockIdx.x, tid = threadIdx.x;
  const int l = tid & 63;

  const int kq = tid & 3, e1 = tid >> 2;        // P1 mapping
  const int wsc = tid >> 4, jsc = tid & 15;     // P2 mapping (16 e's, stride-16 pairs)
  const float4 wih = *(const float4*)(w_ih + (size_t)tid * 4);
  const float bs = b_ih[tid] + b_hh[tid];
  const float4 efc = g_encfc[b * 64 + l];

  const uint4* w1s = g_w1s + tid;
  const uint4* whs = g_whs + tid;

  // ---- LDS init ----
  if (tid < 256) { st_l[tid] = 0u; w2_l[tid] = w2[tid]; }
  if (tid < 64) yh_l[tid] = ((const float4*)yhist)[b * 64 + tid];
  if (tid < 16) fcy_l[tid] = fc_w[(tid >> 2) * 260 + 256 + (tid & 3)];
  if (tid < 4) fcb_l[tid] = fc_b[tid];
#pragma unroll
  for (int i = 0; i < 8; i++) {
    int idx = tid + 1024 * i;  // 8192 payload uints
    int w = idx >> 7, u = idx & 127;
    ep_l[w * 132 + u] = g_ep16[(size_t)(b * 64 + w) * 128 + u];
  }
  float c0 = 0.f, c1 = 0.f;  // c state, thread tid<128 owns d=2tid,2tid+1
  __syncthreads();

  float attw = 0.f;
  const uint4* stq = (const uint4*)st_l;
  for (int t = 0; t < Wn; t++) {
    // ---- phase A: full weight stream (w1 + w_hh) in one go ----
    float a = 0.f;   // hcp partial: e=e1, k in [128*kq, 128*kq+128) over [h|c]
#pragma unroll
    for (int i = 0; i < 16; i++) a = fd2x4u(w1s[i * 1024], stq[16 * kq + i], a);
    float aA = bs;   // gate row tid: full 256-k h-dot (softmax-independent)
#pragma unroll
    for (int i = 0; i < 32; i++) aA = fd2x4u(whs[i * 1024], stq[i], aA);
    a += __shfl_xor(a, 1, 64);
    a += __shfl_xor(a, 2, 64);
    if (kq == 0) hcp_l[e1] = a;
    __syncthreads();  // B1: hcp ready
    // ---- phase B: scores (stride-16 pair interleave: conflict-free LDS) ----
    {
      float s = 0.f;
#pragma unroll
      for (int i = 0; i < 8; i++) {
        int pi = jsc + 16 * i;
        h2 aa = __builtin_bit_cast(h2, ep_l[wsc * 132 + pi]);
        int e0 = 2 * pi;
        s += w2_l[e0] * ftanh((float)aa.x + hcp_l[e0]);
        s += w2_l[e0 + 1] * ftanh((float)aa.y + hcp_l[e0 + 1]);
      }
      s += __shfl_xor(s, 1, 64);
      s += __shfl_xor(s, 2, 64);
      s += __shfl_xor(s, 4, 64);
      s += __shfl_xor(s, 8, 64);
      if ((l & 15) == 0) att_l[wsc] = s;
    }
    __syncthreads();  // B2: scores ready
    // ---- phase C: softmax + ytilde (per-wave redundant) + gate finalize ----
    {
      float sc = att_l[l];
      float m = sc;
#pragma unroll
      for (int dd = 32; dd; dd >>= 1) m = fmaxf(m, __shfl_xor(m, dd, 64));
      float pr = __builtin_exp2f((sc - m) * 1.4426950408889634f);
      float su = pr;
#pragma unroll
      for (int dd = 32; dd; dd >>= 1) su += __shfl_xor(su, dd, 64);
      attw = pr * __builtin_amdgcn_rcpf(su);
    }
    {
      float rx = attw * efc.x, ry = attw * efc.y, rz = attw * efc.z, rw = attw * efc.w;
#pragma unroll
      for (int dd = 32; dd; dd >>= 1) {
        rx += __shfl_xor(rx, dd, 64);
        ry += __shfl_xor(ry, dd, 64);
        rz += __shfl_xor(rz, dd, 64);
        rw += __shfl_xor(rw, dd, 64);
      }
      float4 yv = yh_l[t];
      float4 yt4;
      yt4.x = rx + fcb_l[0] + fcy_l[0] * yv.x + fcy_l[1] * yv.y + fcy_l[2] * yv.z + fcy_l[3] * yv.w;
      yt4.y = ry + fcb_l[1] + fcy_l[4] * yv.x + fcy_l[5] * yv.y + fcy_l[6] * yv.z + fcy_l[7] * yv.w;
      yt4.z = rz + fcb_l[2] + fcy_l[8] * yv.x + fcy_l[9] * yv.y + fcy_l[10] * yv.z + fcy_l[11] * yv.w;
      yt4.w = rw + fcb_l[3] + fcy_l[12] * yv.x + fcy_l[13] * yv.y + fcy_l[14] * yv.z + fcy_l[15] * yv.w;
      aA += dot4(wih, yt4);
      ag_l[tid] = aA;
    }
    __syncthreads();  // B3: gates ready
    // ---- phase D: LSTM elementwise (tid<128, 2 d's each) ----
    if (tid < 128) {
      const int d0 = 2 * tid, d1 = d0 + 1;
      float i0 = fsigm(ag_l[d0]), i1 = fsigm(ag_l[d1]);
      float f0 = fsigm(ag_l[256 + d0]), f1 = fsigm(ag_l[256 + d1]);
      float G0 = ftanh(ag_l[512 + d0]), G1 = ftanh(ag_l[512 + d1]);
      float o0 = fsigm(ag_l[768 + d0]), o1 = fsigm(ag_l[768 + d1]);
      float cn0 = f0 * c0 + i0 * G0, cn1 = f1 * c1 + i1 * G1;
      float hn0 = o0 * ftanh(cn0), hn1 = o1 * ftanh(cn1);
      c0 = cn0; c1 = cn1;
      st_l[tid] = pk(hn0, hn1);
      st_l[128 + tid] = pk(cn0, cn1);
    }
    __syncthreads();  // B4: state updated
  }

  // ---- final: out[b,f] = fcf_h·h + attn·ENCFCF + fcf_b (waves 0..3) ----
  if (tid < 256) {
    const int f = tid >> 6;
    h2 ha = __builtin_bit_cast(h2, st_l[l]);
    h2 hb = __builtin_bit_cast(h2, st_l[64 + l]);
    float v = fcf_w[f * 512 + 2 * l] * (float)ha.x +
              fcf_w[f * 512 + 2 * l + 1] * (float)ha.y +
              fcf_w[f * 512 + 128 + 2 * l] * (float)hb.x +
              fcf_w[f * 512 + 128 + 2 * l + 1] * (float)hb.y;
    float4 fv = g_encfcf[b * 64 + l];
    v += attw * ((const float*)&fv)[f];
#pragma unroll
    for (int dd = 32; dd; dd >>= 1) v += __shfl_xor(v, dd, 64);
    if (l == 0) out[b * 4 + f] = v + fcf_b[f];
  }
}

extern "C" void kernel_launch(void* const* d_in, const int* in_sizes, int n_in,
                              void* d_out, int out_size, void* d_ws, size_t ws_size,
                              hipStream_t stream) {
  (void)in_sizes; (void)n_in; (void)d_ws; (void)ws_size; (void)out_size;
  const float* enc   = (const float*)d_in[0];
  const float* yhist = (const float*)d_in[1];
  const float* w1    = (const float*)d_in[2];
  const float* b1    = (const float*)d_in[3];
  const float* w2    = (const float*)d_in[4];
  // d_in[5] = attn_b2: softmax-invariant -> unused
  const float* w_ih  = (const float*)d_in[6];
  const float* w_hh  = (const float*)d_in[7];
  const float* b_ih  = (const float*)d_in[8];
  const float* b_hh  = (const float*)d_in[9];
  const float* fc_w  = (const float*)d_in[10];
  const float* fc_b  = (const float*)d_in[11];
  const float* fcf_w = (const float*)d_in[12];
  const float* fcf_b = (const float*)d_in[13];
  float* out = (float*)d_out;

  pack_kernel<<<dim3(192), dim3(256), 0, stream>>>(w1, w_hh);
  eproj_kernel<<<dim3(512), dim3(256), 0, stream>>>(enc, w1, b1);
  encfc_kernel<<<dim3(512), dim3(256), 0, stream>>>(enc, fc_w, fcf_w);
  decoder_kernel<<<dim3(Bn), dim3(1024), 0, stream>>>(yhist, w2, w_ih, b_ih, b_hh,
                                                      fc_w, fc_b, fcf_w, fcf_b, out);
}

// Round 9
// 845.311 us; speedup vs baseline: 4.5668x; 4.5668x over previous
//
#include <hip/hip_runtime.h>

#define Bn 128
#define Wn 64

typedef _Float16 h2 __attribute__((ext_vector_type(2)));

// ---- device state (reset kernel clears flags/out each launch) ----
__device__ unsigned g_flag[256];              // partials ready, value = t+1
__device__ unsigned g_post[256][2][768];      // [g][t&1][hcp 256 | gate-for-partner 512]
__device__ unsigned g_ep16[Bn * Wn * 128];    // eproj f16 pairs [b][w][128]
__device__ float4 g_encfc[Bn * Wn];           // fc_w[:, :256] @ enc
__device__ float4 g_encfcf[Bn * Wn];          // fcf_w[:, 256:] @ enc
__device__ uint4 g_wstream[2 * 24576];        // per k-half packed f16 stream (2 x 384 KB)

__device__ __forceinline__ float ftanh(float x) {
  float p = __builtin_exp2f(x * 2.885390081777927f);
  return 1.0f - 2.0f * __builtin_amdgcn_rcpf(p + 1.0f);
}
__device__ __forceinline__ float fsigm(float x) {
  float p = __builtin_exp2f(-x * 1.4426950408889634f);
  return __builtin_amdgcn_rcpf(1.0f + p);
}
__device__ __forceinline__ float dot4(float4 a, float4 b) {
  return a.x * b.x + a.y * b.y + a.z * b.z + a.w * b.w;
}
__device__ __forceinline__ float fd2(unsigned w, unsigned h, float acc) {
  h2 a = __builtin_bit_cast(h2, w), b = __builtin_bit_cast(h2, h);
#if __has_builtin(__builtin_amdgcn_fdot2)
  return __builtin_amdgcn_fdot2(a, b, acc, false);
#else
  return acc + (float)a.x * (float)b.x + (float)a.y * (float)b.y;
#endif
}
__device__ __forceinline__ float fd2x4u(uint4 w, uint4 h, float acc) {
  acc = fd2(w.x, h.x, acc);
  acc = fd2(w.y, h.y, acc);
  acc = fd2(w.z, h.z, acc);
  acc = fd2(w.w, h.w, acc);
  return acc;
}
__device__ __forceinline__ unsigned pk(float a, float b) {
  h2 h = {(_Float16)a, (_Float16)b};
  return __builtin_bit_cast(unsigned, h);
}
__device__ __forceinline__ void ast(unsigned* p, unsigned v) {
  __hip_atomic_store(p, v, __ATOMIC_RELAXED, __HIP_MEMORY_SCOPE_AGENT);
}
__device__ __forceinline__ unsigned ald(unsigned* p) {
  return __hip_atomic_load(p, __ATOMIC_RELAXED, __HIP_MEMORY_SCOPE_AGENT);
}

// ---------------- reset ----------------
__global__ void reset_kernel(float* out) {
  int t = threadIdx.x;
  if (t < 256) g_flag[t] = 0u;
  if (t < 512) out[t] = 0.f;
}

// ---------------- pack: stream layout LIN = ((w*12+s)*4+i)*64 + l ----------------
__global__ __launch_bounds__(256) void pack_kernel(const float* __restrict__ w1,
                                                   const float* __restrict__ w_hh) {
  int idx = blockIdx.x * 256 + threadIdx.x;  // 49152 tasks
  int p = idx / 24576;
  int LIN = idx % 24576;
  int l = LIN & 63;
  int t2 = LIN >> 6;
  int ii = t2 & 3;
  int t3 = t2 >> 2;
  int w = t3 / 12;
  int s = t3 - 12 * w;
  const float* src;
  if (s < 4) {  // w1 region: e-row = w*32+s*8+(l>>3), uint4 u = (l&7)+8i
    int E = w * 32 + s * 8 + (l >> 3);
    int u = (l & 7) + 8 * ii;
    int col = (u < 16) ? (128 * p + 8 * u) : (256 + 128 * p + 8 * (u - 16));
    src = w1 + (size_t)E * 768 + col;
  } else {      // w_hh region: row = w*128+(s-4)*16+(l>>2), uint4 u = (l&3)+4i
    int R = w * 128 + (s - 4) * 16 + (l >> 2);
    int u = (l & 3) + 4 * ii;
    src = w_hh + (size_t)R * 256 + 128 * p + 8 * u;
  }
  uint4 o;
  o.x = pk(src[0], src[1]); o.y = pk(src[2], src[3]);
  o.z = pk(src[4], src[5]); o.w = pk(src[6], src[7]);
  g_wstream[idx] = o;
}

// ---------------- eproj: b1 + W1e @ enc -> f16 pairs ----------------
__global__ __launch_bounds__(256) void eproj_kernel(const float* __restrict__ enc,
                                                    const float* __restrict__ w1,
                                                    const float* __restrict__ b1) {
  __shared__ __align__(16) float4 encs[16][64];
  __shared__ float accs[16][256];
  const int m0 = blockIdx.x * 16;
  const int tid = threadIdx.x;
  const float4* eg = (const float4*)(enc + (size_t)m0 * 256);
#pragma unroll
  for (int i = 0; i < 4; i++) {
    int idx = tid + 256 * i;
    encs[idx >> 6][idx & 63] = eg[idx];
  }
  __syncthreads();
  const int e = tid;
  float acc[16];
#pragma unroll
  for (int i = 0; i < 16; i++) acc[i] = 0.f;
  const float4* wrow = (const float4*)(w1 + e * 768 + 512);
  for (int k4 = 0; k4 < 64; k4++) {
    float4 wv = wrow[k4];
#pragma unroll
    for (int i = 0; i < 16; i++) acc[i] += dot4(wv, encs[i][k4]);
  }
  float bb = b1[e];
#pragma unroll
  for (int i = 0; i < 16; i++) accs[i][e] = acc[i] + bb;
  __syncthreads();
#pragma unroll
  for (int r = 0; r < 8; r++) {
    int idx = r * 256 + tid;
    int i = idx >> 7, jp = idx & 127;
    g_ep16[(size_t)(m0 + i) * 128 + jp] = pk(accs[i][2 * jp], accs[i][2 * jp + 1]);
  }
}

// ---------------- ENCFC / ENCFCF precompute ----------------
__global__ __launch_bounds__(256) void encfc_kernel(const float* __restrict__ enc,
                                                    const float* __restrict__ fc_w,
                                                    const float* __restrict__ fcf_w) {
  __shared__ __align__(16) float4 encs[16][64];
  const int m0 = blockIdx.x * 16;
  const int tid = threadIdx.x;
  const float4* eg = (const float4*)(enc + (size_t)m0 * 256);
#pragma unroll
  for (int i = 0; i < 4; i++) {
    int idx = tid + 256 * i;
    encs[idx >> 6][idx & 63] = eg[idx];
  }
  __syncthreads();
  if (tid < 128) {
    const int r = tid >> 3, o = tid & 7;
    const float* wr = (o < 4) ? (fc_w + o * 260) : (fcf_w + (o - 4) * 512 + 256);
    const float4* w4 = (const float4*)wr;
    float a = 0.f;
#pragma unroll 8
    for (int k = 0; k < 64; k++) a += dot4(w4[k], encs[r][k]);
    if (o < 4) ((float*)&g_encfc[m0 + r])[o] = a;
    else ((float*)&g_encfcf[m0 + r])[o - 4] = a;
  }
}

// ---------------- decoder: k-split pair, DMA-streamed weights, 1 sync round ----------------
#define AS1C(pp) ((const __attribute__((address_space(1))) void*)(pp))
#define AS3C(pp) ((__attribute__((address_space(3))) void*)(pp))

#define DMAISSUE(s) do {                                                                   \
    __builtin_amdgcn_global_load_lds(AS1C(gsrc + (s) * 256 + 0 * 64),                      \
                                     AS3C(&sbuf[wid][(s) % 3][0][0]), 16, 0, 0);           \
    __builtin_amdgcn_global_load_lds(AS1C(gsrc + (s) * 256 + 1 * 64),                      \
                                     AS3C(&sbuf[wid][(s) % 3][1][0]), 16, 0, 0);           \
    __builtin_amdgcn_global_load_lds(AS1C(gsrc + (s) * 256 + 2 * 64),                      \
                                     AS3C(&sbuf[wid][(s) % 3][2][0]), 16, 0, 0);           \
    __builtin_amdgcn_global_load_lds(AS1C(gsrc + (s) * 256 + 3 * 64),                      \
                                     AS3C(&sbuf[wid][(s) % 3][3][0]), 16, 0, 0);           \
  } while (0)

#define WAITVM(n) do { asm volatile("s_waitcnt vmcnt(" #n ")" ::: "memory");               \
                       __builtin_amdgcn_sched_barrier(0); } while (0)
#define WAITLG    do { asm volatile("s_waitcnt lgkmcnt(0)" ::: "memory");                  \
                       __builtin_amdgcn_sched_barrier(0); } while (0)

#define CONS_W1(s) do {                                                                    \
    float acc = 0.f;                                                                       \
    { uint4 wv = sbuf[wid][(s) % 3][0][l]; acc = fd2x4u(wv, stq[(l & 7) + 0], acc); }      \
    { uint4 wv = sbuf[wid][(s) % 3][1][l]; acc = fd2x4u(wv, stq[(l & 7) + 8], acc); }      \
    { uint4 wv = sbuf[wid][(s) % 3][2][l]; acc = fd2x4u(wv, stq[(l & 7) + 16], acc); }     \
    { uint4 wv = sbuf[wid][(s) % 3][3][l]; acc = fd2x4u(wv, stq[(l & 7) + 24], acc); }     \
    acc += __shfl_xor(acc, 1, 64);                                                         \
    acc += __shfl_xor(acc, 2, 64);                                                         \
    acc += __shfl_xor(acc, 4, 64);                                                         \
    if ((l & 7) == 0) hcp_par[wid * 32 + (s) * 8 + (l >> 3)] = acc;                        \
  } while (0)

#define CONS_WH(s) do {                                                                    \
    float acc = 0.f;                                                                       \
    { uint4 wv = sbuf[wid][(s) % 3][0][l]; acc = fd2x4u(wv, stq[(l & 3) + 0], acc); }      \
    { uint4 wv = sbuf[wid][(s) % 3][1][l]; acc = fd2x4u(wv, stq[(l & 3) + 4], acc); }      \
    { uint4 wv = sbuf[wid][(s) % 3][2][l]; acc = fd2x4u(wv, stq[(l & 3) + 8], acc); }      \
    { uint4 wv = sbuf[wid][(s) % 3][3][l]; acc = fd2x4u(wv, stq[(l & 3) + 12], acc); }     \
    acc += __shfl_xor(acc, 1, 64);                                                         \
    acc += __shfl_xor(acc, 2, 64);                                                         \
    if ((l & 3) == 0) gate_par[wid * 128 + ((s) - 4) * 16 + (l >> 2)] = acc;               \
  } while (0)

__global__ __launch_bounds__(512, 2) void decoder_kernel(
    const float* __restrict__ yhist, const float* __restrict__ w2,
    const float* __restrict__ w_ih, const float* __restrict__ b_ih,
    const float* __restrict__ b_hh,
    const float* __restrict__ fc_w, const float* __restrict__ fc_b,
    const float* __restrict__ fcf_w, const float* __restrict__ fcf_b,
    float* __restrict__ out) {
  __shared__ __align__(16) uint4 sbuf[8][3][4][64];   // 96 KB DMA ring (3 slots/wave)
  __shared__ __align__(16) unsigned st_l[128];        // own-half state: h pairs 0..63, c 64..127
  __shared__ float hcp_par[256], hcp_in[256];
  __shared__ __align__(16) float gate_par[1024];      // own-k partials, all rows
  __shared__ __align__(16) float gpar_in[512];        // partner partials for my rows (j=tid)
  __shared__ float att_par[8][64];
  __shared__ float att_w[64];
  __shared__ __align__(16) float ytil[4];
  __shared__ unsigned ep_l[64 * 129];                 // stride 129: 2-way (free) banks
  __shared__ __align__(16) float4 yh_l[64];
  __shared__ float w2_l[256];
  __shared__ float fcy_l[16];
  __shared__ float fcb_l[4];

  const int g = blockIdx.x, tid = threadIdx.x;
  const int b = g & 127, p = g >> 7, other = g ^ 128;
  const int wid = tid >> 6, l = tid & 63;

  const int q = tid >> 7, dl = tid & 127;
  const int R = q * 256 + 128 * p + dl;               // my gate row
  const float4 wih = *(const float4*)(w_ih + (size_t)R * 4);
  const float bs = b_ih[R] + b_hh[R];
  const float4 efc = g_encfc[b * 64 + l];

  const uint4* gsrc = g_wstream + (size_t)p * 24576 + (size_t)wid * 3072 + l;

  // ---- LDS init ----
  if (tid < 128) st_l[tid] = 0u;
  if (tid < 256) w2_l[tid] = w2[tid];
  if (tid < 64) yh_l[tid] = ((const float4*)yhist)[b * 64 + tid];
  if (tid < 16) fcy_l[tid] = fc_w[(tid >> 2) * 260 + 256 + (tid & 3)];
  if (tid < 4) fcb_l[tid] = fc_b[tid];
#pragma unroll
  for (int i = 0; i < 16; i++) {
    int idx = tid + 512 * i;  // 8192 pairs
    int w = idx >> 7, u = idx & 127;
    ep_l[w * 129 + u] = g_ep16[(size_t)(b * 64 + w) * 128 + u];
  }
  float c0 = 0.f, c1 = 0.f;  // tid<64 owns d = 128p+2*tid, +1
  __syncthreads();

  const uint4* stq = (const uint4*)st_l;

  for (int t = 0; t < Wn; t++) {
    // ======== stream phase: 12 x 4KB slots, 3-deep DMA pipeline, no barriers ========
    DMAISSUE(0); DMAISSUE(1); DMAISSUE(2);
    WAITVM(8); CONS_W1(0); WAITLG; DMAISSUE(3);
    WAITVM(8); CONS_W1(1); WAITLG; DMAISSUE(4);
    WAITVM(8); CONS_W1(2); WAITLG; DMAISSUE(5);
    WAITVM(8); CONS_W1(3); WAITLG; DMAISSUE(6);
    WAITVM(8); CONS_WH(4); WAITLG; DMAISSUE(7);
    WAITVM(8); CONS_WH(5); WAITLG; DMAISSUE(8);
    WAITVM(8); CONS_WH(6); WAITLG; DMAISSUE(9);
    WAITVM(8); CONS_WH(7); WAITLG; DMAISSUE(10);
    WAITVM(8); CONS_WH(8); WAITLG; DMAISSUE(11);
    WAITVM(8); CONS_WH(9);
    WAITVM(4); CONS_WH(10);
    WAITVM(0); CONS_WH(11);
    __syncthreads();  // B1: partials complete

    // ======== one exchange round: post (wave 0) / poll+fetch (wave 1) ========
    const int tb = t & 1;
    if (wid == 0) {
      unsigned* dst = &g_post[g][tb][0];
      const int j1 = 4 * l, j2 = 4 * l + 256;
      const int R1 = (j1 >> 7) * 256 + 128 * (1 - p) + (j1 & 127);
      const int R2 = (j2 >> 7) * 256 + 128 * (1 - p) + (j2 & 127);
#pragma unroll
      for (int k = 0; k < 4; k++) ast(dst + 4 * l + k, __builtin_bit_cast(unsigned, hcp_par[4 * l + k]));
#pragma unroll
      for (int k = 0; k < 4; k++) ast(dst + 256 + 4 * l + k, __builtin_bit_cast(unsigned, gate_par[R1 + k]));
#pragma unroll
      for (int k = 0; k < 4; k++) ast(dst + 512 + 4 * l + k, __builtin_bit_cast(unsigned, gate_par[R2 + k]));
      asm volatile("s_waitcnt vmcnt(0)" ::: "memory");
      if (l == 0) ast(&g_flag[g], (unsigned)(t + 1));
    } else if (wid == 1) {
      while ((int)ald(&g_flag[other]) < t + 1) __builtin_amdgcn_s_sleep(2);
      asm volatile("" ::: "memory");
      unsigned* src = &g_post[other][tb][0];
#pragma unroll
      for (int k = 0; k < 4; k++) hcp_in[4 * l + k] = __builtin_bit_cast(float, ald(src + 4 * l + k));
#pragma unroll
      for (int k = 0; k < 4; k++) gpar_in[4 * l + k] = __builtin_bit_cast(float, ald(src + 256 + 4 * l + k));
#pragma unroll
      for (int k = 0; k < 4; k++) gpar_in[256 + 4 * l + k] = __builtin_bit_cast(float, ald(src + 512 + 4 * l + k));
    }
    __syncthreads();  // B2: hcp_in / gpar_in ready

    // ======== P2: score partials, row-per-lane (conflict-free) ========
    {
      const unsigned* eprow = &ep_l[l * 129 + wid * 16];
      float s_acc = 0.f;
#pragma unroll
      for (int i = 0; i < 16; i++) {
        int e0 = 2 * (wid * 16 + i);
        h2 aa = __builtin_bit_cast(h2, eprow[i]);
        float hc0 = hcp_par[e0] + hcp_in[e0];
        float hc1 = hcp_par[e0 + 1] + hcp_in[e0 + 1];
        s_acc += w2_l[e0] * ftanh((float)aa.x + hc0);
        s_acc += w2_l[e0 + 1] * ftanh((float)aa.y + hc1);
      }
      att_par[wid][l] = s_acc;
    }
    __syncthreads();  // B3

    // ======== softmax + ytilde (wave 0) ========
    if (wid == 0) {
      float sc = 0.f;
#pragma unroll
      for (int k = 0; k < 8; k++) sc += att_par[k][l];
      float m = sc;
#pragma unroll
      for (int dd = 32; dd; dd >>= 1) m = fmaxf(m, __shfl_xor(m, dd, 64));
      float pr = __builtin_exp2f((sc - m) * 1.4426950408889634f);
      float su = pr;
#pragma unroll
      for (int dd = 32; dd; dd >>= 1) su += __shfl_xor(su, dd, 64);
      float aw = pr * __builtin_amdgcn_rcpf(su);
      att_w[l] = aw;
      float rx = aw * efc.x, ry = aw * efc.y, rz = aw * efc.z, rw = aw * efc.w;
#pragma unroll
      for (int dd = 32; dd; dd >>= 1) {
        rx += __shfl_xor(rx, dd, 64);
        ry += __shfl_xor(ry, dd, 64);
        rz += __shfl_xor(rz, dd, 64);
        rw += __shfl_xor(rw, dd, 64);
      }
      if (l == 0) {
        float4 yv = yh_l[t];
        ytil[0] = rx + fcb_l[0] + fcy_l[0] * yv.x + fcy_l[1] * yv.y + fcy_l[2] * yv.z + fcy_l[3] * yv.w;
        ytil[1] = ry + fcb_l[1] + fcy_l[4] * yv.x + fcy_l[5] * yv.y + fcy_l[6] * yv.z + fcy_l[7] * yv.w;
        ytil[2] = rz + fcb_l[2] + fcy_l[8] * yv.x + fcy_l[9] * yv.y + fcy_l[10] * yv.z + fcy_l[11] * yv.w;
        ytil[3] = rw + fcb_l[3] + fcy_l[12] * yv.x + fcy_l[13] * yv.y + fcy_l[14] * yv.z + fcy_l[15] * yv.w;
      }
    }
    __syncthreads();  // B4: ytil ready

    // ======== gates finalize (own 512 rows) ========
    {
      float4 yt4 = *(const float4*)ytil;
      float val = bs + dot4(wih, yt4) + gate_par[R] + gpar_in[tid];
      gpar_in[tid] = val;  // reuse as gate-value array [q*128+dl]
    }
    __syncthreads();  // B5: gates ready

    // ======== LSTM elementwise (own d-half) ========
    if (tid < 64) {
      const int d0 = 2 * tid, d1 = d0 + 1;
      float i0 = fsigm(gpar_in[d0]), i1 = fsigm(gpar_in[d1]);
      float f0 = fsigm(gpar_in[128 + d0]), f1 = fsigm(gpar_in[128 + d1]);
      float G0 = ftanh(gpar_in[256 + d0]), G1 = ftanh(gpar_in[256 + d1]);
      float o0 = fsigm(gpar_in[384 + d0]), o1 = fsigm(gpar_in[384 + d1]);
      float cn0 = f0 * c0 + i0 * G0, cn1 = f1 * c1 + i1 * G1;
      float hn0 = o0 * ftanh(cn0), hn1 = o1 * ftanh(cn1);
      c0 = cn0; c1 = cn1;
      st_l[tid] = pk(hn0, hn1);
      st_l[64 + tid] = pk(cn0, cn1);
    }
    __syncthreads();  // B6: state updated for next stream
  }

  // ---- final: out[b,f] += fcf_h(own half)·h + [p==0](attn·ENCFCF + fcf_b) ----
  if (wid < 4) {
    const int f = wid;
    h2 hh = __builtin_bit_cast(h2, st_l[l]);
    float v = fcf_w[f * 512 + 128 * p + 2 * l] * (float)hh.x +
              fcf_w[f * 512 + 128 * p + 2 * l + 1] * (float)hh.y;
    if (p == 0) {
      float4 fv = g_encfcf[b * 64 + l];
      v += att_w[l] * ((const float*)&fv)[f];
    }
#pragma unroll
    for (int dd = 32; dd; dd >>= 1) v += __shfl_xor(v, dd, 64);
    if (l == 0) atomicAdd(out + b * 4 + f, v + ((p == 0) ? fcf_b[f] : 0.f));
  }
}

extern "C" void kernel_launch(void* const* d_in, const int* in_sizes, int n_in,
                              void* d_out, int out_size, void* d_ws, size_t ws_size,
                              hipStream_t stream) {
  (void)in_sizes; (void)n_in; (void)d_ws; (void)ws_size; (void)out_size;
  const float* enc   = (const float*)d_in[0];
  const float* yhist = (const float*)d_in[1];
  const float* w1    = (const float*)d_in[2];
  const float* b1    = (const float*)d_in[3];
  const float* w2    = (const float*)d_in[4];
  // d_in[5] = attn_b2: softmax-invariant -> unused
  const float* w_ih  = (const float*)d_in[6];
  const float* w_hh  = (const float*)d_in[7];
  const float* b_ih  = (const float*)d_in[8];
  const float* b_hh  = (const float*)d_in[9];
  const float* fc_w  = (const float*)d_in[10];
  const float* fc_b  = (const float*)d_in[11];
  const float* fcf_w = (const float*)d_in[12];
  const float* fcf_b = (const float*)d_in[13];
  float* out = (float*)d_out;

  reset_kernel<<<dim3(1), dim3(512), 0, stream>>>(out);
  pack_kernel<<<dim3(192), dim3(256), 0, stream>>>(w1, w_hh);
  eproj_kernel<<<dim3(512), dim3(256), 0, stream>>>(enc, w1, b1);
  encfc_kernel<<<dim3(512), dim3(256), 0, stream>>>(enc, fc_w, fcf_w);
  decoder_kernel<<<dim3(256), dim3(512), 0, stream>>>(yhist, w2, w_ih, b_ih, b_hh,
                                                      fc_w, fc_b, fcf_w, fcf_b, out);
}